// Round 16
// baseline (358.552 us; speedup 1.0000x reference)
//
#include <hip/hip_runtime.h>
#include <hip/hip_fp16.h>
#include <math.h>

#define NTOT   64000
#define NNODE  1000
#define NBATCH 64
#define NSEQ   12
#define NE     1024000

typedef _Float16 half8 __attribute__((ext_vector_type(8)));
typedef float f32x4 __attribute__((ext_vector_type(4)));

__device__ __forceinline__ float lrelu(float x){ return x > 0.f ? x : 0.2f*x; }
__device__ __forceinline__ float sigmoidf_(float x){ return 1.f/(1.f+__expf(-x)); }

// ---------------- GAT (blocks<250) + edge count (blocks>=250), fused ----------------
// Round-15: Ws inner product vectorized 4-wide (ds_read_b128) -> LDS instr 4608->~1200.
__global__ void __launch_bounds__(256) k_gat_count(const float* __restrict__ x, const float* __restrict__ Wg,
                       const float* __restrict__ att_s, const float* __restrict__ att_d,
                       __half* __restrict__ hfeat, float* __restrict__ asrc, float* __restrict__ adst,
                       const int* __restrict__ ei, int* __restrict__ cnt){
  if (blockIdx.x >= 250){
    int e = (blockIdx.x - 250)*256 + threadIdx.x;
    if (e < NE) atomicAdd(&cnt[ei[NE + e]], 1);
    return;
  }
  __shared__ __align__(16) float Ws[48*96];
  __shared__ __align__(16) float as_s[96];
  __shared__ __align__(16) float ad_s[96];
  for (int i = threadIdx.x; i < 48*96; i += 256) Ws[i] = Wg[i];
  if (threadIdx.x < 96){ as_s[threadIdx.x] = att_s[threadIdx.x]; ad_s[threadIdx.x] = att_d[threadIdx.x]; }
  __syncthreads();
  int n = blockIdx.x * 256 + threadIdx.x;
  float xr[48];
  const float4* xv = (const float4*)(x + (size_t)n*48);
  #pragma unroll
  for (int q = 0; q < 12; ++q){ float4 v = xv[q]; xr[q*4]=v.x; xr[q*4+1]=v.y; xr[q*4+2]=v.z; xr[q*4+3]=v.w; }
  float a0=0.f,a1=0.f,d0=0.f,d1=0.f;
  __half* hrow = hfeat + (size_t)n*96;
  for (int j4 = 0; j4 < 96; j4 += 4){
    float ax=0.f, ay=0.f, az=0.f, aw=0.f;
    #pragma unroll 8
    for (int k = 0; k < 48; ++k){
      float4 wv = *(const float4*)&Ws[k*96 + j4];
      float xk = xr[k];
      ax += wv.x*xk; ay += wv.y*xk; az += wv.z*xk; aw += wv.w*xk;
    }
    __half2 p0; p0.x = __float2half(ax); p0.y = __float2half(ay);
    __half2 p1; p1.x = __float2half(az); p1.y = __float2half(aw);
    *(__half2*)(hrow + j4)     = p0;
    *(__half2*)(hrow + j4 + 2) = p1;
    float4 as4 = *(const float4*)&as_s[j4];
    float4 ad4 = *(const float4*)&ad_s[j4];
    float sdot = ax*as4.x + ay*as4.y + az*as4.z + aw*as4.w;
    float ddot = ax*ad4.x + ay*ad4.y + az*ad4.z + aw*ad4.w;
    if (j4 < 48){ a0 += sdot; d0 += ddot; }
    else        { a1 += sdot; d1 += ddot; }
  }
  asrc[n*2]=a0; asrc[n*2+1]=a1; adst[n*2]=d0; adst[n*2+1]=d1;
}

// ---------------- CSR build ----------------
__global__ void __launch_bounds__(256) k_scan1(const int* __restrict__ cnt, int* __restrict__ wsum){
  int w = (blockIdx.x*256 + threadIdx.x) >> 6;
  int lane = threadIdx.x & 63;
  int v = cnt[w*64 + lane];
  int t = v;
  #pragma unroll
  for (int d = 1; d < 64; d <<= 1) t += __shfl_xor(t, d);
  if (lane == 0) wsum[w] = t;
}

__global__ void __launch_bounds__(1024) k_scan2(int* __restrict__ wsum){
  __shared__ int tmp[1024];
  int k = threadIdx.x;
  int v = (k < 1000) ? wsum[k] : 0;
  tmp[k] = v; __syncthreads();
  for (int d = 1; d < 1024; d <<= 1){
    int t = (k >= d) ? tmp[k-d] : 0;
    __syncthreads();
    tmp[k] += t;
    __syncthreads();
  }
  if (k < 1000) wsum[k] = tmp[k] - v;
}

__global__ void __launch_bounds__(256) k_scan3(const int* __restrict__ cnt, const int* __restrict__ wpre,
                                               int* __restrict__ offs, int* __restrict__ cursor){
  int w = (blockIdx.x*256 + threadIdx.x) >> 6;
  int lane = threadIdx.x & 63;
  int i = w*64 + lane;
  int v = cnt[i];
  int x = v;
  #pragma unroll
  for (int d = 1; d < 64; d <<= 1){
    int t = __shfl_up(x, d);
    if (lane >= d) x += t;
  }
  int excl = wpre[w] + x - v;
  offs[i] = excl; cursor[i] = excl;
  if (i == NTOT-1) offs[NTOT] = excl + v;
}

__global__ void k_scatter(const int* __restrict__ ei, int* __restrict__ cursor, int* __restrict__ csr){
  int e = blockIdx.x*256 + threadIdx.x;
  if (e < NE){
    int d = ei[NE + e], s = ei[e];
    int pos = atomicAdd(&cursor[d], 1);
    csr[pos] = s;
  }
}

// ---------------- per-node fused softmax-weighted aggregation (single edge pass) ----------------
// Round-15: gather unroll 4 -> 8 for deeper memory-level parallelism (L3 latency hiding).
__global__ void __launch_bounds__(256) k_node(const __half* __restrict__ hf, const float* __restrict__ asrc,
                      const float* __restrict__ adst, const int* __restrict__ offs,
                      const int* __restrict__ csr, const float* __restrict__ bias,
                      _Float16* __restrict__ xseqh){
  __shared__ float gsh[4][96];
  int wv = threadIdx.x >> 6, lane = threadIdx.x & 63;
  int n = blockIdx.x*4 + wv;
  int off = offs[n], deg = offs[n+1] - off;
  const float2* as2 = (const float2*)asrc;
  float2 adn = ((const float2*)adst)[n];
  float2 asn = as2[n];
  float es0 = __expf(lrelu(asn.x + adn.x));
  float es1 = __expf(lrelu(asn.y + adn.y));
  if (lane < 48){
    int cl = lane;
    bool h0 = (lane < 24);
    float wself = h0 ? es0 : es1;
    float ssum = wself;
    float2 acc;
    {
      __half2 r2 = *(const __half2*)(hf + (size_t)n*96 + 2*cl);
      float2 r = __half22float2(r2);
      acc.x = r.x*wself; acc.y = r.y*wself;
    }
    int i = 0;
    for (; i + 8 <= deg; i += 8){
      int ss[8];
      #pragma unroll
      for (int j = 0; j < 8; ++j) ss[j] = csr[off+i+j];
      float2 aa[8];
      #pragma unroll
      for (int j = 0; j < 8; ++j) aa[j] = as2[ss[j]];
      __half2 rr[8];
      #pragma unroll
      for (int j = 0; j < 8; ++j) rr[j] = *(const __half2*)(hf + (size_t)ss[j]*96 + 2*cl);
      #pragma unroll
      for (int j = 0; j < 8; ++j){
        float w0 = __expf(lrelu(aa[j].x + adn.x));
        float w1 = __expf(lrelu(aa[j].y + adn.y));
        float ws = h0 ? w0 : w1;
        float2 r = __half22float2(rr[j]);
        acc.x += r.x*ws; acc.y += r.y*ws;
        ssum += ws;
      }
    }
    for (; i + 4 <= deg; i += 4){
      int ss[4];
      #pragma unroll
      for (int j = 0; j < 4; ++j) ss[j] = csr[off+i+j];
      float2 aa[4];
      #pragma unroll
      for (int j = 0; j < 4; ++j) aa[j] = as2[ss[j]];
      __half2 rr[4];
      #pragma unroll
      for (int j = 0; j < 4; ++j) rr[j] = *(const __half2*)(hf + (size_t)ss[j]*96 + 2*cl);
      #pragma unroll
      for (int j = 0; j < 4; ++j){
        float w0 = __expf(lrelu(aa[j].x + adn.x));
        float w1 = __expf(lrelu(aa[j].y + adn.y));
        float ws = h0 ? w0 : w1;
        float2 r = __half22float2(rr[j]);
        acc.x += r.x*ws; acc.y += r.y*ws;
        ssum += ws;
      }
    }
    for (; i < deg; ++i){
      int s = csr[off+i];
      float2 a = as2[s];
      __half2 r2 = *(const __half2*)(hf + (size_t)s*96 + 2*cl);
      float w0 = __expf(lrelu(a.x + adn.x));
      float w1 = __expf(lrelu(a.y + adn.y));
      float ws = h0 ? w0 : w1;
      float2 r = __half22float2(r2);
      acc.x += r.x*ws; acc.y += r.y*ws;
      ssum += ws;
    }
    float inv = 1.f/(ssum + 1e-16f);
    gsh[wv][2*cl] = acc.x*inv; gsh[wv][2*cl+1] = acc.y*inv;
  }
  __syncthreads();
  if (lane < 48){
    float g = 0.5f*(gsh[wv][lane] + gsh[wv][48+lane]) + bias[lane];
    int b = n / 1000, node = n - b*1000;
    int t = lane >> 2, f = lane & 3;
    xseqh[((size_t)(t*64 + b))*4000 + node*4 + f] = (_Float16)g;
  }
}

// ---------------- fused prep: Wih1 fp32->fp16 + LSTM weight K-major fp16 transpose ----------------
__global__ void __launch_bounds__(256) k_prep(const float* __restrict__ Wih1,
                    const float* __restrict__ Whh1, const float* __restrict__ Wih2,
                    const float* __restrict__ Whh2,
                    _Float16* __restrict__ Bh, __half* __restrict__ dst){
  int blk = blockIdx.x;
  if (blk < 4000){
    int i = blk*256 + threadIdx.x;
    float4 v = *(const float4*)(Wih1 + (size_t)i*4);
    union { _Float16 h[4]; uint2 u; } o;
    o.h[0] = (_Float16)v.x; o.h[1] = (_Float16)v.y;
    o.h[2] = (_Float16)v.z; o.h[3] = (_Float16)v.w;
    *(uint2*)(Bh + (size_t)i*4) = o.u;
    return;
  }
  int i = (blk-4000)*256 + threadIdx.x;
  if (i < 262144){ int q = i>>10, r = i&1023; dst[i] = __float2half(Whh1[r*256+q]); return; }
  i -= 262144;
  if (i < 131072){ int q = i>>9, r = i&511; dst[262144+i] = __float2half(Wih2[r*256+q]); return; }
  i -= 131072;
  if (i < 65536){ int q = i>>9, r = i&511; dst[393216+i] = __float2half(Whh2[(size_t)r*128+q]); }
}

// ---------------- GEMM1 on matrix cores, split-K=5 ----------------
__global__ void __launch_bounds__(256) k_gemm1h(const _Float16* __restrict__ A,
                        const _Float16* __restrict__ B, float* __restrict__ part){
  __shared__ _Float16 As[64*40];
  __shared__ _Float16 Bs[64*40];
  int tid = threadIdx.x;
  int w = tid >> 6, l = tid & 63;
  int m0 = blockIdx.x*64, n0 = blockIdx.y*64;
  int k0 = blockIdx.z*800;
  int fr = l & 15, fk = (l >> 4)*8;
  f32x4 acc0 = {0.f,0.f,0.f,0.f}, acc1 = acc0, acc2 = acc0, acc3 = acc0;
  int ra = tid >> 2, ca = (tid & 3)*8;
  const _Float16* Ap = A + (size_t)(m0+ra)*4000 + k0 + ca;
  const _Float16* Bp = B + (size_t)(n0+ra)*4000 + k0 + ca;
  _Float16* Asw = &As[ra*40 + ca];
  _Float16* Bsw = &Bs[ra*40 + ca];
  half8 pa = *(const half8*)Ap;
  half8 pb = *(const half8*)Bp;
  for (int kk = 0; kk < 800; kk += 32){
    *(half8*)Asw = pa;
    *(half8*)Bsw = pb;
    __syncthreads();
    if (kk + 32 < 800){
      pa = *(const half8*)(Ap + kk + 32);
      pb = *(const half8*)(Bp + kk + 32);
    }
    half8 af  = *(const half8*)&As[(w*16 + fr)*40 + fk];
    half8 bf0 = *(const half8*)&Bs[( 0 + fr)*40 + fk];
    half8 bf1 = *(const half8*)&Bs[(16 + fr)*40 + fk];
    half8 bf2 = *(const half8*)&Bs[(32 + fr)*40 + fk];
    half8 bf3 = *(const half8*)&Bs[(48 + fr)*40 + fk];
    acc0 = __builtin_amdgcn_mfma_f32_16x16x32_f16(af, bf0, acc0, 0, 0, 0);
    acc1 = __builtin_amdgcn_mfma_f32_16x16x32_f16(af, bf1, acc1, 0, 0, 0);
    acc2 = __builtin_amdgcn_mfma_f32_16x16x32_f16(af, bf2, acc2, 0, 0, 0);
    acc3 = __builtin_amdgcn_mfma_f32_16x16x32_f16(af, bf3, acc3, 0, 0, 0);
    __syncthreads();
  }
  int mrow = m0 + w*16 + (l >> 4)*4;
  int ncol = n0 + (l & 15);
  #pragma unroll
  for (int r = 0; r < 4; ++r){
    float* cp = part + ((size_t)blockIdx.z*768 + mrow + r)*1024 + ncol;
    cp[0]  = acc0[r];
    cp[16] = acc1[r];
    cp[32] = acc2[r];
    cp[48] = acc3[r];
  }
}

__device__ __forceinline__ void mac8(float* acc, uint4 wv, float hq){
  const __half2* hp = (const __half2*)&wv;
  float2 f0 = __half22float2(hp[0]);
  float2 f1 = __half22float2(hp[1]);
  float2 f2 = __half22float2(hp[2]);
  float2 f3 = __half22float2(hp[3]);
  acc[0] += f0.x*hq; acc[1] += f0.y*hq;
  acc[2] += f1.x*hq; acc[3] += f1.y*hq;
  acc[4] += f2.x*hq; acc[5] += f2.y*hq;
  acc[6] += f3.x*hq; acc[7] += f3.y*hq;
}

// ---------------- fused 2-layer LSTM, software-pipelined + inline split-K reduce ----------------
// Round-15: k_red5 fused into the xg load (b1 + 5 partials, coalesced, overlaps the
// weight stream) -> one less kernel + no xw1 round-trip.
__global__ void __launch_bounds__(1024) k_lstm(
    const float* __restrict__ part, const float* __restrict__ b1,
    const __half* __restrict__ W1, const __half* __restrict__ W2i,
    const __half* __restrict__ W2h, const float* __restrict__ b2,
    float* __restrict__ h2o){
  __shared__ float h1s[256];
  __shared__ float h2s[128];
  __shared__ __align__(16) float pA[8192];
  __shared__ __align__(16) float pB[8192];
  int t = threadIdx.x;
  int b = blockIdx.x;
  int kk1 = t >> 7, c1c = (t & 127) * 8;
  int kk2 = t >> 6, c2c = (t & 63) * 8;
  int u2 = t - 256;
  float cc1 = 0.f, cc2 = 0.f;
  float b2r[4] = {0.f,0.f,0.f,0.f};
  if (t >= 256 && t < 384){
    #pragma unroll
    for (int gi = 0; gi < 4; ++gi) b2r[gi] = b2[gi*128 + u2];
  }
  float b1r[4] = {0.f,0.f,0.f,0.f};
  if (t < 256){
    #pragma unroll
    for (int gi = 0; gi < 4; ++gi) b1r[gi] = b1[gi*256 + t];
  }
  if (t < 256) h1s[t] = 0.f;
  if (t < 128) h2s[t] = 0.f;
  __syncthreads();

  for (int k = 0; k <= NSEQ; ++k){
    float xg[4] = {0.f,0.f,0.f,0.f};
    if (k < NSEQ && t < 256){
      const float* pr = part + ((size_t)k*64 + b)*1024 + t;
      #pragma unroll
      for (int gi = 0; gi < 4; ++gi){
        float s = b1r[gi];
        #pragma unroll
        for (int ss = 0; ss < 5; ++ss) s += pr[(size_t)ss*786432 + gi*256];
        xg[gi] = s;
      }
    }
    if (k < NSEQ){
      float acc[8] = {0,0,0,0,0,0,0,0};
      const __half* wp = W1 + (size_t)(kk1*32)*1024 + c1c;
      const float* hb = &h1s[kk1*32];
      #pragma unroll 4
      for (int q = 0; q < 32; ++q)
        mac8(acc, *(const uint4*)(wp + (size_t)q*1024), hb[q]);
      float4 w0; w0.x=acc[0]; w0.y=acc[1]; w0.z=acc[2]; w0.w=acc[3];
      float4 w1; w1.x=acc[4]; w1.y=acc[5]; w1.z=acc[6]; w1.w=acc[7];
      *(float4*)&pA[kk1*1024 + c1c]     = w0;
      *(float4*)&pA[kk1*1024 + c1c + 4] = w1;
    }
    if (k >= 1){
      float acch[8] = {0,0,0,0,0,0,0,0};
      const __half* wi = W2i + (size_t)(kk2*16)*512 + c2c;
      const float* hb1 = &h1s[kk2*16];
      #pragma unroll 4
      for (int q = 0; q < 16; ++q)
        mac8(acch, *(const uint4*)(wi + (size_t)q*512), hb1[q]);
      const __half* wh = W2h + (size_t)(kk2*8)*512 + c2c;
      const float* hb2 = &h2s[kk2*8];
      #pragma unroll 4
      for (int q = 0; q < 8; ++q)
        mac8(acch, *(const uint4*)(wh + (size_t)q*512), hb2[q]);
      float4 w0; w0.x=acch[0]; w0.y=acch[1]; w0.z=acch[2]; w0.w=acch[3];
      float4 w1; w1.x=acch[4]; w1.y=acch[5]; w1.z=acch[6]; w1.w=acch[7];
      *(float4*)&pB[kk2*512 + c2c]     = w0;
      *(float4*)&pB[kk2*512 + c2c + 4] = w1;
    }
    __syncthreads();
    if (k < NSEQ && t < 256){
      float g[4];
      #pragma unroll
      for (int gi = 0; gi < 4; ++gi){
        float s = xg[gi];
        #pragma unroll
        for (int kk = 0; kk < 8; ++kk) s += pA[kk*1024 + gi*256 + t];
        g[gi] = s;
      }
      float i_ = sigmoidf_(g[0]);
      float f_ = sigmoidf_(g[1]);
      float gg = tanhf(g[2]);
      float o_ = sigmoidf_(g[3]);
      cc1 = f_*cc1 + i_*gg;
      h1s[t] = o_*tanhf(cc1);
    }
    if (k >= 1 && t >= 256 && t < 384){
      float g[4];
      #pragma unroll
      for (int gi = 0; gi < 4; ++gi){
        float s = b2r[gi];
        #pragma unroll
        for (int kk = 0; kk < 16; ++kk) s += pB[kk*512 + gi*128 + u2];
        g[gi] = s;
      }
      float i_ = sigmoidf_(g[0]);
      float f_ = sigmoidf_(g[1]);
      float gg = tanhf(g[2]);
      float o_ = sigmoidf_(g[3]);
      cc2 = f_*cc2 + i_*gg;
      h2s[u2] = o_*tanhf(cc2);
    }
    __syncthreads();
  }
  if (t >= 256 && t < 384) h2o[(size_t)b*128 + u2] = h2s[u2];
}

// ---------------- output projection: 8-batch register reuse of Wout rows ----------------
__global__ void __launch_bounds__(256) k_out(const float* __restrict__ h2, const float* __restrict__ Wout,
                     const float* __restrict__ bout, float* __restrict__ out){
  __shared__ __align__(16) float hs[8][128];
  int t = threadIdx.x;
  int b0 = blockIdx.y * 8;
  #pragma unroll
  for (int r = 0; r < 4; ++r){
    int idx = r*256 + t;
    hs[idx >> 7][idx & 127] = h2[(size_t)(b0 + (idx >> 7))*128 + (idx & 127)];
  }
  __syncthreads();
  if (t >= 250) return;
  int j = blockIdx.x*250 + t;
  const float4* w = (const float4*)(Wout + (size_t)j*128);
  float bj = bout[j];
  float d[8];
  #pragma unroll
  for (int bb = 0; bb < 8; ++bb) d[bb] = bj;
  for (int q = 0; q < 32; ++q){
    float4 wv = w[q];
    #pragma unroll
    for (int bb = 0; bb < 8; ++bb){
      float4 hv = ((const float4*)hs[bb])[q];
      d[bb] += wv.x*hv.x + wv.y*hv.y + wv.z*hv.z + wv.w*hv.w;
    }
  }
  #pragma unroll
  for (int bb = 0; bb < 8; ++bb)
    out[(size_t)(b0+bb)*2000 + j] = d[bb];
}

extern "C" void kernel_launch(void* const* d_in, const int* in_sizes, int n_in,
                              void* d_out, int out_size, void* d_ws, size_t ws_size,
                              hipStream_t stream){
  const float* x     = (const float*)d_in[0];
  const int*   ei    = (const int*)d_in[1];
  const float* Wg    = (const float*)d_in[2];
  const float* att_s = (const float*)d_in[3];
  const float* att_d = (const float*)d_in[4];
  const float* gb    = (const float*)d_in[5];
  const float* Wih1  = (const float*)d_in[6];
  const float* Whh1  = (const float*)d_in[7];
  const float* b1    = (const float*)d_in[8];
  const float* Wih2  = (const float*)d_in[9];
  const float* Whh2  = (const float*)d_in[10];
  const float* b2    = (const float*)d_in[11];
  const float* Wout  = (const float*)d_in[12];
  const float* bout  = (const float*)d_in[13];
  float* out = (float*)d_out;

  char* w = (char*)d_ws;
  _Float16* xseqh = (_Float16*)w;                     // 6,144,000 B (region 12.29 MB)
  char*  hbase = w + 12288000;                        // hfeat region: 24,576,000 B
  __half* hfeath = (__half*)hbase;                    // 12,288,000 B (fp16), alive until k_node
  _Float16* Bh  = (_Float16*)hbase;                   // 8,192,000 B (fp16 Wih1), after k_node
  __half* W1h   = (__half*)(hbase + 11337728);        //   917,504 B
  float* h2o    = (float*)(hbase + 12255232);         //    32,768 B
  // split-K partials: 15,728,640 B; overlaps CSR/p2 region (dead when gemm1h runs).
  float* part   = (float*)(hbase + 12288000);
  char*  p2 = w + 12288000 + 24576000;
  float* asrc   = (float*)(p2);
  float* adst   = (float*)(p2 + 512000);
  int*   cnt    = (int*)(p2 + 1024000);
  int*   offs   = (int*)(p2 + 1280000);
  int*   cursor = (int*)(p2 + 1536256);
  int*   csr    = (int*)(p2 + 1792256);
  int*   wsum   = csr;   // 4 KB alias: scan1/2/3 use it BEFORE k_scatter writes csr

  hipMemsetAsync(cnt, 0, NTOT*sizeof(int), stream);

  k_gat_count<<<4250, 256, 0, stream>>>(x, Wg, att_s, att_d, hfeath, asrc, adst, ei, cnt);
  k_scan1<<<250, 256, 0, stream>>>(cnt, wsum);
  k_scan2<<<1, 1024, 0, stream>>>(wsum);
  k_scan3<<<250, 256, 0, stream>>>(cnt, wsum, offs, cursor);
  k_scatter<<<4000, 256, 0, stream>>>(ei, cursor, csr);
  k_node<<<16000, 256, 0, stream>>>(hfeath, asrc, adst, offs, csr, gb, xseqh);

  k_prep<<<5792, 256, 0, stream>>>(Wih1, Whh1, Wih2, Whh2, Bh, W1h);
  k_gemm1h<<<dim3(12,16,5), 256, 0, stream>>>(xseqh, Bh, part);

  k_lstm<<<NBATCH, 1024, 0, stream>>>(part, b1, W1h, W1h + 262144, W1h + 393216, b2, h2o);
  k_out<<<dim3(8,8), 256, 0, stream>>>(h2o, Wout, bout, out);
}

// Round 17
// 351.347 us; speedup vs baseline: 1.0205x; 1.0205x over previous
//
#include <hip/hip_runtime.h>
#include <hip/hip_fp16.h>
#include <math.h>

#define NTOT   64000
#define NNODE  1000
#define NBATCH 64
#define NSEQ   12
#define NE     1024000

typedef _Float16 half8 __attribute__((ext_vector_type(8)));
typedef float f32x4 __attribute__((ext_vector_type(4)));

__device__ __forceinline__ float lrelu(float x){ return x > 0.f ? x : 0.2f*x; }
__device__ __forceinline__ float sigmoidf_(float x){ return 1.f/(1.f+__expf(-x)); }

// ---------------- GAT (blocks<250) + edge count (blocks>=250), fused ----------------
// Round-15: Ws inner product vectorized 4-wide (ds_read_b128) -> LDS instr 4608->~1200.
__global__ void __launch_bounds__(256) k_gat_count(const float* __restrict__ x, const float* __restrict__ Wg,
                       const float* __restrict__ att_s, const float* __restrict__ att_d,
                       __half* __restrict__ hfeat, float* __restrict__ asrc, float* __restrict__ adst,
                       const int* __restrict__ ei, int* __restrict__ cnt){
  if (blockIdx.x >= 250){
    int e = (blockIdx.x - 250)*256 + threadIdx.x;
    if (e < NE) atomicAdd(&cnt[ei[NE + e]], 1);
    return;
  }
  __shared__ __align__(16) float Ws[48*96];
  __shared__ __align__(16) float as_s[96];
  __shared__ __align__(16) float ad_s[96];
  for (int i = threadIdx.x; i < 48*96; i += 256) Ws[i] = Wg[i];
  if (threadIdx.x < 96){ as_s[threadIdx.x] = att_s[threadIdx.x]; ad_s[threadIdx.x] = att_d[threadIdx.x]; }
  __syncthreads();
  int n = blockIdx.x * 256 + threadIdx.x;
  float xr[48];
  const float4* xv = (const float4*)(x + (size_t)n*48);
  #pragma unroll
  for (int q = 0; q < 12; ++q){ float4 v = xv[q]; xr[q*4]=v.x; xr[q*4+1]=v.y; xr[q*4+2]=v.z; xr[q*4+3]=v.w; }
  float a0=0.f,a1=0.f,d0=0.f,d1=0.f;
  __half* hrow = hfeat + (size_t)n*96;
  for (int j4 = 0; j4 < 96; j4 += 4){
    float ax=0.f, ay=0.f, az=0.f, aw=0.f;
    #pragma unroll 8
    for (int k = 0; k < 48; ++k){
      float4 wv = *(const float4*)&Ws[k*96 + j4];
      float xk = xr[k];
      ax += wv.x*xk; ay += wv.y*xk; az += wv.z*xk; aw += wv.w*xk;
    }
    __half2 p0; p0.x = __float2half(ax); p0.y = __float2half(ay);
    __half2 p1; p1.x = __float2half(az); p1.y = __float2half(aw);
    *(__half2*)(hrow + j4)     = p0;
    *(__half2*)(hrow + j4 + 2) = p1;
    float4 as4 = *(const float4*)&as_s[j4];
    float4 ad4 = *(const float4*)&ad_s[j4];
    float sdot = ax*as4.x + ay*as4.y + az*as4.z + aw*as4.w;
    float ddot = ax*ad4.x + ay*ad4.y + az*ad4.z + aw*ad4.w;
    if (j4 < 48){ a0 += sdot; d0 += ddot; }
    else        { a1 += sdot; d1 += ddot; }
  }
  asrc[n*2]=a0; asrc[n*2+1]=a1; adst[n*2]=d0; adst[n*2+1]=d1;
}

// ---------------- CSR build ----------------
__global__ void __launch_bounds__(256) k_scan1(const int* __restrict__ cnt, int* __restrict__ wsum){
  int w = (blockIdx.x*256 + threadIdx.x) >> 6;
  int lane = threadIdx.x & 63;
  int v = cnt[w*64 + lane];
  int t = v;
  #pragma unroll
  for (int d = 1; d < 64; d <<= 1) t += __shfl_xor(t, d);
  if (lane == 0) wsum[w] = t;
}

__global__ void __launch_bounds__(1024) k_scan2(int* __restrict__ wsum){
  __shared__ int tmp[1024];
  int k = threadIdx.x;
  int v = (k < 1000) ? wsum[k] : 0;
  tmp[k] = v; __syncthreads();
  for (int d = 1; d < 1024; d <<= 1){
    int t = (k >= d) ? tmp[k-d] : 0;
    __syncthreads();
    tmp[k] += t;
    __syncthreads();
  }
  if (k < 1000) wsum[k] = tmp[k] - v;
}

__global__ void __launch_bounds__(256) k_scan3(const int* __restrict__ cnt, const int* __restrict__ wpre,
                                               int* __restrict__ offs, int* __restrict__ cursor){
  int w = (blockIdx.x*256 + threadIdx.x) >> 6;
  int lane = threadIdx.x & 63;
  int i = w*64 + lane;
  int v = cnt[i];
  int x = v;
  #pragma unroll
  for (int d = 1; d < 64; d <<= 1){
    int t = __shfl_up(x, d);
    if (lane >= d) x += t;
  }
  int excl = wpre[w] + x - v;
  offs[i] = excl; cursor[i] = excl;
  if (i == NTOT-1) offs[NTOT] = excl + v;
}

__global__ void k_scatter(const int* __restrict__ ei, int* __restrict__ cursor, int* __restrict__ csr){
  int e = blockIdx.x*256 + threadIdx.x;
  if (e < NE){
    int d = ei[NE + e], s = ei[e];
    int pos = atomicAdd(&cursor[d], 1);
    csr[pos] = s;
  }
}

// ---------------- per-node fused softmax-weighted aggregation (single edge pass) ----------------
// Round-15: gather unroll 4 -> 8 for deeper memory-level parallelism (L3 latency hiding).
__global__ void __launch_bounds__(256) k_node(const __half* __restrict__ hf, const float* __restrict__ asrc,
                      const float* __restrict__ adst, const int* __restrict__ offs,
                      const int* __restrict__ csr, const float* __restrict__ bias,
                      _Float16* __restrict__ xseqh){
  __shared__ float gsh[4][96];
  int wv = threadIdx.x >> 6, lane = threadIdx.x & 63;
  int n = blockIdx.x*4 + wv;
  int off = offs[n], deg = offs[n+1] - off;
  const float2* as2 = (const float2*)asrc;
  float2 adn = ((const float2*)adst)[n];
  float2 asn = as2[n];
  float es0 = __expf(lrelu(asn.x + adn.x));
  float es1 = __expf(lrelu(asn.y + adn.y));
  if (lane < 48){
    int cl = lane;
    bool h0 = (lane < 24);
    float wself = h0 ? es0 : es1;
    float ssum = wself;
    float2 acc;
    {
      __half2 r2 = *(const __half2*)(hf + (size_t)n*96 + 2*cl);
      float2 r = __half22float2(r2);
      acc.x = r.x*wself; acc.y = r.y*wself;
    }
    int i = 0;
    for (; i + 8 <= deg; i += 8){
      int ss[8];
      #pragma unroll
      for (int j = 0; j < 8; ++j) ss[j] = csr[off+i+j];
      float2 aa[8];
      #pragma unroll
      for (int j = 0; j < 8; ++j) aa[j] = as2[ss[j]];
      __half2 rr[8];
      #pragma unroll
      for (int j = 0; j < 8; ++j) rr[j] = *(const __half2*)(hf + (size_t)ss[j]*96 + 2*cl);
      #pragma unroll
      for (int j = 0; j < 8; ++j){
        float w0 = __expf(lrelu(aa[j].x + adn.x));
        float w1 = __expf(lrelu(aa[j].y + adn.y));
        float ws = h0 ? w0 : w1;
        float2 r = __half22float2(rr[j]);
        acc.x += r.x*ws; acc.y += r.y*ws;
        ssum += ws;
      }
    }
    for (; i + 4 <= deg; i += 4){
      int ss[4];
      #pragma unroll
      for (int j = 0; j < 4; ++j) ss[j] = csr[off+i+j];
      float2 aa[4];
      #pragma unroll
      for (int j = 0; j < 4; ++j) aa[j] = as2[ss[j]];
      __half2 rr[4];
      #pragma unroll
      for (int j = 0; j < 4; ++j) rr[j] = *(const __half2*)(hf + (size_t)ss[j]*96 + 2*cl);
      #pragma unroll
      for (int j = 0; j < 4; ++j){
        float w0 = __expf(lrelu(aa[j].x + adn.x));
        float w1 = __expf(lrelu(aa[j].y + adn.y));
        float ws = h0 ? w0 : w1;
        float2 r = __half22float2(rr[j]);
        acc.x += r.x*ws; acc.y += r.y*ws;
        ssum += ws;
      }
    }
    for (; i < deg; ++i){
      int s = csr[off+i];
      float2 a = as2[s];
      __half2 r2 = *(const __half2*)(hf + (size_t)s*96 + 2*cl);
      float w0 = __expf(lrelu(a.x + adn.x));
      float w1 = __expf(lrelu(a.y + adn.y));
      float ws = h0 ? w0 : w1;
      float2 r = __half22float2(r2);
      acc.x += r.x*ws; acc.y += r.y*ws;
      ssum += ws;
    }
    float inv = 1.f/(ssum + 1e-16f);
    gsh[wv][2*cl] = acc.x*inv; gsh[wv][2*cl+1] = acc.y*inv;
  }
  __syncthreads();
  if (lane < 48){
    float g = 0.5f*(gsh[wv][lane] + gsh[wv][48+lane]) + bias[lane];
    int b = n / 1000, node = n - b*1000;
    int t = lane >> 2, f = lane & 3;
    xseqh[((size_t)(t*64 + b))*4000 + node*4 + f] = (_Float16)g;
  }
}

// ---------------- fused prep: Wih1 fp32->fp16 + LSTM weight K-major fp16 transpose ----------------
__global__ void __launch_bounds__(256) k_prep(const float* __restrict__ Wih1,
                    const float* __restrict__ Whh1, const float* __restrict__ Wih2,
                    const float* __restrict__ Whh2,
                    _Float16* __restrict__ Bh, __half* __restrict__ dst){
  int blk = blockIdx.x;
  if (blk < 4000){
    int i = blk*256 + threadIdx.x;
    float4 v = *(const float4*)(Wih1 + (size_t)i*4);
    union { _Float16 h[4]; uint2 u; } o;
    o.h[0] = (_Float16)v.x; o.h[1] = (_Float16)v.y;
    o.h[2] = (_Float16)v.z; o.h[3] = (_Float16)v.w;
    *(uint2*)(Bh + (size_t)i*4) = o.u;
    return;
  }
  int i = (blk-4000)*256 + threadIdx.x;
  if (i < 262144){ int q = i>>10, r = i&1023; dst[i] = __float2half(Whh1[r*256+q]); return; }
  i -= 262144;
  if (i < 131072){ int q = i>>9, r = i&511; dst[262144+i] = __float2half(Wih2[r*256+q]); return; }
  i -= 131072;
  if (i < 65536){ int q = i>>9, r = i&511; dst[393216+i] = __float2half(Whh2[(size_t)r*128+q]); }
}

// ---------------- GEMM1 on matrix cores, split-K=5 ----------------
__global__ void __launch_bounds__(256) k_gemm1h(const _Float16* __restrict__ A,
                        const _Float16* __restrict__ B, float* __restrict__ part){
  __shared__ _Float16 As[64*40];
  __shared__ _Float16 Bs[64*40];
  int tid = threadIdx.x;
  int w = tid >> 6, l = tid & 63;
  int m0 = blockIdx.x*64, n0 = blockIdx.y*64;
  int k0 = blockIdx.z*800;
  int fr = l & 15, fk = (l >> 4)*8;
  f32x4 acc0 = {0.f,0.f,0.f,0.f}, acc1 = acc0, acc2 = acc0, acc3 = acc0;
  int ra = tid >> 2, ca = (tid & 3)*8;
  const _Float16* Ap = A + (size_t)(m0+ra)*4000 + k0 + ca;
  const _Float16* Bp = B + (size_t)(n0+ra)*4000 + k0 + ca;
  _Float16* Asw = &As[ra*40 + ca];
  _Float16* Bsw = &Bs[ra*40 + ca];
  half8 pa = *(const half8*)Ap;
  half8 pb = *(const half8*)Bp;
  for (int kk = 0; kk < 800; kk += 32){
    *(half8*)Asw = pa;
    *(half8*)Bsw = pb;
    __syncthreads();
    if (kk + 32 < 800){
      pa = *(const half8*)(Ap + kk + 32);
      pb = *(const half8*)(Bp + kk + 32);
    }
    half8 af  = *(const half8*)&As[(w*16 + fr)*40 + fk];
    half8 bf0 = *(const half8*)&Bs[( 0 + fr)*40 + fk];
    half8 bf1 = *(const half8*)&Bs[(16 + fr)*40 + fk];
    half8 bf2 = *(const half8*)&Bs[(32 + fr)*40 + fk];
    half8 bf3 = *(const half8*)&Bs[(48 + fr)*40 + fk];
    acc0 = __builtin_amdgcn_mfma_f32_16x16x32_f16(af, bf0, acc0, 0, 0, 0);
    acc1 = __builtin_amdgcn_mfma_f32_16x16x32_f16(af, bf1, acc1, 0, 0, 0);
    acc2 = __builtin_amdgcn_mfma_f32_16x16x32_f16(af, bf2, acc2, 0, 0, 0);
    acc3 = __builtin_amdgcn_mfma_f32_16x16x32_f16(af, bf3, acc3, 0, 0, 0);
    __syncthreads();
  }
  int mrow = m0 + w*16 + (l >> 4)*4;
  int ncol = n0 + (l & 15);
  #pragma unroll
  for (int r = 0; r < 4; ++r){
    float* cp = part + ((size_t)blockIdx.z*768 + mrow + r)*1024 + ncol;
    cp[0]  = acc0[r];
    cp[16] = acc1[r];
    cp[32] = acc2[r];
    cp[48] = acc3[r];
  }
}

__device__ __forceinline__ void mac8(float* acc, uint4 wv, float hq){
  const __half2* hp = (const __half2*)&wv;
  float2 f0 = __half22float2(hp[0]);
  float2 f1 = __half22float2(hp[1]);
  float2 f2 = __half22float2(hp[2]);
  float2 f3 = __half22float2(hp[3]);
  acc[0] += f0.x*hq; acc[1] += f0.y*hq;
  acc[2] += f1.x*hq; acc[3] += f1.y*hq;
  acc[4] += f2.x*hq; acc[5] += f2.y*hq;
  acc[6] += f3.x*hq; acc[7] += f3.y*hq;
}

// ---------------- fused 2-layer LSTM, software-pipelined + inline split-K reduce ----------------
// Round-15: k_red5 fused into the xg load (b1 + 5 partials, coalesced, overlaps the
// weight stream) -> one less kernel + no xw1 round-trip.
__global__ void __launch_bounds__(1024) k_lstm(
    const float* __restrict__ part, const float* __restrict__ b1,
    const __half* __restrict__ W1, const __half* __restrict__ W2i,
    const __half* __restrict__ W2h, const float* __restrict__ b2,
    float* __restrict__ h2o){
  __shared__ float h1s[256];
  __shared__ float h2s[128];
  __shared__ __align__(16) float pA[8192];
  __shared__ __align__(16) float pB[8192];
  int t = threadIdx.x;
  int b = blockIdx.x;
  int kk1 = t >> 7, c1c = (t & 127) * 8;
  int kk2 = t >> 6, c2c = (t & 63) * 8;
  int u2 = t - 256;
  float cc1 = 0.f, cc2 = 0.f;
  float b2r[4] = {0.f,0.f,0.f,0.f};
  if (t >= 256 && t < 384){
    #pragma unroll
    for (int gi = 0; gi < 4; ++gi) b2r[gi] = b2[gi*128 + u2];
  }
  float b1r[4] = {0.f,0.f,0.f,0.f};
  if (t < 256){
    #pragma unroll
    for (int gi = 0; gi < 4; ++gi) b1r[gi] = b1[gi*256 + t];
  }
  if (t < 256) h1s[t] = 0.f;
  if (t < 128) h2s[t] = 0.f;
  __syncthreads();

  for (int k = 0; k <= NSEQ; ++k){
    float xg[4] = {0.f,0.f,0.f,0.f};
    if (k < NSEQ && t < 256){
      const float* pr = part + ((size_t)k*64 + b)*1024 + t;
      #pragma unroll
      for (int gi = 0; gi < 4; ++gi){
        float s = b1r[gi];
        #pragma unroll
        for (int ss = 0; ss < 5; ++ss) s += pr[(size_t)ss*786432 + gi*256];
        xg[gi] = s;
      }
    }
    if (k < NSEQ){
      float acc[8] = {0,0,0,0,0,0,0,0};
      const __half* wp = W1 + (size_t)(kk1*32)*1024 + c1c;
      const float* hb = &h1s[kk1*32];
      #pragma unroll 4
      for (int q = 0; q < 32; ++q)
        mac8(acc, *(const uint4*)(wp + (size_t)q*1024), hb[q]);
      float4 w0; w0.x=acc[0]; w0.y=acc[1]; w0.z=acc[2]; w0.w=acc[3];
      float4 w1; w1.x=acc[4]; w1.y=acc[5]; w1.z=acc[6]; w1.w=acc[7];
      *(float4*)&pA[kk1*1024 + c1c]     = w0;
      *(float4*)&pA[kk1*1024 + c1c + 4] = w1;
    }
    if (k >= 1){
      float acch[8] = {0,0,0,0,0,0,0,0};
      const __half* wi = W2i + (size_t)(kk2*16)*512 + c2c;
      const float* hb1 = &h1s[kk2*16];
      #pragma unroll 4
      for (int q = 0; q < 16; ++q)
        mac8(acch, *(const uint4*)(wi + (size_t)q*512), hb1[q]);
      const __half* wh = W2h + (size_t)(kk2*8)*512 + c2c;
      const float* hb2 = &h2s[kk2*8];
      #pragma unroll 4
      for (int q = 0; q < 8; ++q)
        mac8(acch, *(const uint4*)(wh + (size_t)q*512), hb2[q]);
      float4 w0; w0.x=acch[0]; w0.y=acch[1]; w0.z=acch[2]; w0.w=acch[3];
      float4 w1; w1.x=acch[4]; w1.y=acch[5]; w1.z=acch[6]; w1.w=acch[7];
      *(float4*)&pB[kk2*512 + c2c]     = w0;
      *(float4*)&pB[kk2*512 + c2c + 4] = w1;
    }
    __syncthreads();
    if (k < NSEQ && t < 256){
      float g[4];
      #pragma unroll
      for (int gi = 0; gi < 4; ++gi){
        float s = xg[gi];
        #pragma unroll
        for (int kk = 0; kk < 8; ++kk) s += pA[kk*1024 + gi*256 + t];
        g[gi] = s;
      }
      float i_ = sigmoidf_(g[0]);
      float f_ = sigmoidf_(g[1]);
      float gg = tanhf(g[2]);
      float o_ = sigmoidf_(g[3]);
      cc1 = f_*cc1 + i_*gg;
      h1s[t] = o_*tanhf(cc1);
    }
    if (k >= 1 && t >= 256 && t < 384){
      float g[4];
      #pragma unroll
      for (int gi = 0; gi < 4; ++gi){
        float s = b2r[gi];
        #pragma unroll
        for (int kk = 0; kk < 16; ++kk) s += pB[kk*512 + gi*128 + u2];
        g[gi] = s;
      }
      float i_ = sigmoidf_(g[0]);
      float f_ = sigmoidf_(g[1]);
      float gg = tanhf(g[2]);
      float o_ = sigmoidf_(g[3]);
      cc2 = f_*cc2 + i_*gg;
      h2s[u2] = o_*tanhf(cc2);
    }
    __syncthreads();
  }
  if (t >= 256 && t < 384) h2o[(size_t)b*128 + u2] = h2s[u2];
}

// ---------------- output projection: 8-batch register reuse of Wout rows ----------------
__global__ void __launch_bounds__(256) k_out(const float* __restrict__ h2, const float* __restrict__ Wout,
                     const float* __restrict__ bout, float* __restrict__ out){
  __shared__ __align__(16) float hs[8][128];
  int t = threadIdx.x;
  int b0 = blockIdx.y * 8;
  #pragma unroll
  for (int r = 0; r < 4; ++r){
    int idx = r*256 + t;
    hs[idx >> 7][idx & 127] = h2[(size_t)(b0 + (idx >> 7))*128 + (idx & 127)];
  }
  __syncthreads();
  if (t >= 250) return;
  int j = blockIdx.x*250 + t;
  const float4* w = (const float4*)(Wout + (size_t)j*128);
  float bj = bout[j];
  float d[8];
  #pragma unroll
  for (int bb = 0; bb < 8; ++bb) d[bb] = bj;
  for (int q = 0; q < 32; ++q){
    float4 wv = w[q];
    #pragma unroll
    for (int bb = 0; bb < 8; ++bb){
      float4 hv = ((const float4*)hs[bb])[q];
      d[bb] += wv.x*hv.x + wv.y*hv.y + wv.z*hv.z + wv.w*hv.w;
    }
  }
  #pragma unroll
  for (int bb = 0; bb < 8; ++bb)
    out[(size_t)(b0+bb)*2000 + j] = d[bb];
}

extern "C" void kernel_launch(void* const* d_in, const int* in_sizes, int n_in,
                              void* d_out, int out_size, void* d_ws, size_t ws_size,
                              hipStream_t stream){
  const float* x     = (const float*)d_in[0];
  const int*   ei    = (const int*)d_in[1];
  const float* Wg    = (const float*)d_in[2];
  const float* att_s = (const float*)d_in[3];
  const float* att_d = (const float*)d_in[4];
  const float* gb    = (const float*)d_in[5];
  const float* Wih1  = (const float*)d_in[6];
  const float* Whh1  = (const float*)d_in[7];
  const float* b1    = (const float*)d_in[8];
  const float* Wih2  = (const float*)d_in[9];
  const float* Whh2  = (const float*)d_in[10];
  const float* b2    = (const float*)d_in[11];
  const float* Wout  = (const float*)d_in[12];
  const float* bout  = (const float*)d_in[13];
  float* out = (float*)d_out;

  char* w = (char*)d_ws;
  _Float16* xseqh = (_Float16*)w;                     // 6,144,000 B (region 12.29 MB)
  char*  hbase = w + 12288000;                        // hfeat region: 24,576,000 B
  __half* hfeath = (__half*)hbase;                    // 12,288,000 B (fp16), alive until k_node
  _Float16* Bh  = (_Float16*)hbase;                   // 8,192,000 B (fp16 Wih1), after k_node
  __half* W1h   = (__half*)(hbase + 11337728);        //   917,504 B
  float* h2o    = (float*)(hbase + 12255232);         //    32,768 B
  // split-K partials: 15,728,640 B; overlaps CSR/p2 region (dead when gemm1h runs).
  float* part   = (float*)(hbase + 12288000);
  char*  p2 = w + 12288000 + 24576000;
  float* asrc   = (float*)(p2);
  float* adst   = (float*)(p2 + 512000);
  int*   cnt    = (int*)(p2 + 1024000);
  int*   offs   = (int*)(p2 + 1280000);
  int*   cursor = (int*)(p2 + 1536256);
  int*   csr    = (int*)(p2 + 1792256);
  int*   wsum   = csr;   // 4 KB alias: scan1/2/3 use it BEFORE k_scatter writes csr

  hipMemsetAsync(cnt, 0, NTOT*sizeof(int), stream);

  k_gat_count<<<4250, 256, 0, stream>>>(x, Wg, att_s, att_d, hfeath, asrc, adst, ei, cnt);
  k_scan1<<<250, 256, 0, stream>>>(cnt, wsum);
  k_scan2<<<1, 1024, 0, stream>>>(wsum);
  k_scan3<<<250, 256, 0, stream>>>(cnt, wsum, offs, cursor);
  k_scatter<<<4000, 256, 0, stream>>>(ei, cursor, csr);
  k_node<<<16000, 256, 0, stream>>>(hfeath, asrc, adst, offs, csr, gb, xseqh);

  k_prep<<<5792, 256, 0, stream>>>(Wih1, Whh1, Wih2, Whh2, Bh, W1h);
  k_gemm1h<<<dim3(12,16,5), 256, 0, stream>>>(xseqh, Bh, part);

  k_lstm<<<NBATCH, 1024, 0, stream>>>(part, b1, W1h, W1h + 262144, W1h + 393216, b2, h2o);
  k_out<<<dim3(8,8), 256, 0, stream>>>(h2o, Wout, bout, out);
}